// Round 9
// baseline (280.176 us; speedup 1.0000x reference)
//
#include <hip/hip_runtime.h>

#define EMBED 128
#define NCODE 10000
#define NSAMP 16384
#define NCODE_PAD 10240
#define NSPLIT 8
#define SPLIT_CODES 1280
#define NCHUNK 20                 // chunks per split, 64 codes each
#define CHUNK_ELEMS 8192          // ushorts per chunk per (h|l): 2mb*8ks*2kh*256
#define OUT_ELEMS (NSAMP * EMBED)
#define TAU 0.002f                // ~28 sigma of full split-bf16 pairwise error

typedef float f32x16 __attribute__((ext_vector_type(16)));
typedef short s16x8 __attribute__((ext_vector_type(8)));
typedef unsigned short ushort_t;
typedef unsigned long long u64;

// ---- ws byte offsets (~12.4 MB) ----
#define OFF_AH  0                 // codes hi bf16, swizzled (2.62 MB)
#define OFF_AL  2621440           // codes lo bf16
#define OFF_CT  5242880           // CT fp32 [n][k] (5.24 MB)
#define OFF_CN  10485760          // cnorm fp32 [10240]
#define OFF_KEY 10526720          // candKey u64 [16384][8]
#define OFF_C2  11575296          // cand2 u32 [16384][8]
#define OFF_IDX 12099584
#define OFF_RL  12165120          // rlist i32 [16384]: m | (splitmask<<16)
#define OFF_CNT 12230656
#define OFF_LOSS 12361792         // lossbuf f32 [64]

__device__ __forceinline__ unsigned short f2bf(float f) {   // RNE fp32->bf16
    unsigned u = __float_as_uint(f);
    return (unsigned short)((u + 0x7fffu + ((u >> 16) & 1u)) >> 16);
}
__device__ __forceinline__ float bf2f(unsigned short h) {
    return __uint_as_float(((unsigned)h) << 16);
}
__device__ __forceinline__ unsigned ordf(float f) {         // order-preserving fp32->u32
    unsigned u = __float_as_uint(f);
    return (u & 0x80000000u) ? ~u : (u | 0x80000000u);
}
__device__ __forceinline__ float unordf(unsigned o) {
    return __uint_as_float((o & 0x80000000u) ? (o ^ 0x80000000u) : ~o);
}

// ---- fused prep: codes -> split-bf16 A-streams + CT fp32 + cnorm ----
// block = 16 codes x 16 dim-groups; cnorm via LDS tree-reduce during the
// conversion pass (no second strided read of C). Also zeroes loss/counter.
__global__ __launch_bounds__(256) void prep_all(const float* __restrict__ C,
                                                ushort_t* __restrict__ Ah,
                                                ushort_t* __restrict__ Al,
                                                float* __restrict__ CT,
                                                float* __restrict__ cnorm,
                                                float* __restrict__ out,
                                                int* __restrict__ counter,
                                                float* __restrict__ lossbuf) {
    __shared__ float red[256];
    const int t  = threadIdx.x;
    const int nl = t & 15;            // code within block
    const int kg = t >> 4;            // 0..15 dim-group
    const int n  = blockIdx.x * 16 + nl;   // 640 blocks
    if (blockIdx.x == 0) {
        if (t == 0) { out[OUT_ELEMS] = 0.f; *counter = 0; }
        if (t < 64) lossbuf[t] = 0.f;
    }

    const int split = n / SPLIT_CODES;
    const int rem   = n % SPLIT_CODES;
    const int chunk = rem >> 6;
    const int mb    = (rem >> 5) & 1;
    const int row   = rem & 31;
    const int ks = kg >> 1, kh = kg & 1;
    const size_t eoff = (size_t)(split * NCHUNK + chunk) * CHUNK_ELEMS
                      + (size_t)(mb * 4096 + (ks * 2 + kh) * 256 + row * 8);
    const int k0 = kg * 8;
    float f[8];
    float s = 0.f;
#pragma unroll
    for (int j = 0; j < 8; ++j) {
        f[j] = (n < NCODE) ? C[(size_t)(k0 + j) * NCODE + n] : 0.f;
        s = fmaf(f[j], f[j], s);
    }
    *(float4*)(CT + (size_t)n * EMBED + k0)     = make_float4(f[0], f[1], f[2], f[3]);
    *(float4*)(CT + (size_t)n * EMBED + k0 + 4) = make_float4(f[4], f[5], f[6], f[7]);
    s16x8 vh, vl;
#pragma unroll
    for (int j = 0; j < 8; ++j) {
        unsigned short h = f2bf(f[j]);
        vh[j] = (short)h;
        vl[j] = (short)f2bf(f[j] - bf2f(h));
    }
    *(s16x8*)(Ah + eoff) = vh;
    *(s16x8*)(Al + eoff) = vl;

    // cnorm: reduce s over the 16 dim-groups of each code
    red[t] = s;
    __syncthreads();
    if (t < 128) red[t] += red[t + 128];
    __syncthreads();
    if (t < 64) red[t] += red[t + 64];
    __syncthreads();
    if (t < 32) red[t] += red[t + 32];
    __syncthreads();
    if (t < 16) {
        const int nn = blockIdx.x * 16 + t;
        cnorm[nn] = (nn < NCODE) ? (red[t] + red[t + 16]) : 3.0e38f;
    }
}

// ---- main: persistent-X (B, -2x split h+l), codes (A, split h+l) LDS dbuf ----
// dist = cnorm (exact, epilogue) + [AhBh + AhBl + AlBh]. Argmin per-lane.
// Shell frozen at R18 (measured: 120.5-124 us, MfmaUtil 49, no spill).
__global__ __launch_bounds__(256, 2) void vq7(const float* __restrict__ X,
                                              const ushort_t* __restrict__ Ah,
                                              const ushort_t* __restrict__ Al,
                                              const float* __restrict__ cnorm,
                                              u64* __restrict__ candKey,
                                              unsigned* __restrict__ cand2) {
    __shared__ ushort_t Bs[2 * 2 * CHUNK_ELEMS];   // 64 KB: buf{0,1} x {h,l}
    __shared__ float cns[SPLIT_CODES];             // 5 KB cnorm slice
    const int t    = threadIdx.x;
    const int lane = t & 63;
    const int wave = t >> 6;
    const int ln   = lane & 31;
    const int kh   = lane >> 5;
    const int split = blockIdx.y;
    const int m0    = blockIdx.x * 256;
    const int sbase = split * SPLIT_CODES;

    // ---- persistent B frags: (-2x) RNE-split hi+lo (128 VGPR) ----
    s16x8 bh[2][8], bl[2][8];
#pragma unroll
    for (int g = 0; g < 2; ++g) {
        int m = m0 + wave * 64 + g * 32 + ln;
#pragma unroll
        for (int ks = 0; ks < 8; ++ks) {
            const float* src = X + (size_t)m * EMBED + ks * 16 + kh * 8;
            float4 f0 = *(const float4*)src;
            float4 f1 = *(const float4*)(src + 4);
            float f[8] = {f0.x, f0.y, f0.z, f0.w, f1.x, f1.y, f1.z, f1.w};
            s16x8 vh, vl;
#pragma unroll
            for (int j = 0; j < 8; ++j) {
                float v = -2.f * f[j];
                unsigned short h = f2bf(v);
                vh[j] = (short)h;
                vl[j] = (short)f2bf(v - bf2f(h));
            }
            bh[g][ks] = vh;
            bl[g][ks] = vl;
        }
    }

    // cnorm slice -> LDS (visible after the prologue __syncthreads)
    for (int i = t; i < SPLIT_CODES; i += 256) cns[i] = cnorm[sbase + i];

    float v1[2] = {3.4e38f, 3.4e38f}, v2[2] = {3.4e38f, 3.4e38f};
    int   j1[2] = {0, 0};

    auto ldsw = (__attribute__((address_space(3))) ushort_t*)Bs;
    const int woff = wave * 2048;              // 4 KB slice per wave per {h,l}
    const size_t chbase = (size_t)(split * NCHUNK) * CHUNK_ELEMS;

    auto stage = [&](int cc, int buf) {
        const size_t sb = chbase + (size_t)cc * CHUNK_ELEMS;
        const ushort_t* sh = Ah + sb + woff + lane * 8;
        const ushort_t* sl = Al + sb + woff + lane * 8;
        const int db = buf * 2 * CHUNK_ELEMS + woff;
#pragma unroll
        for (int i = 0; i < 4; ++i) {
            __builtin_amdgcn_global_load_lds(
                (const __attribute__((address_space(1))) void*)(sh + i * 512),
                (__attribute__((address_space(3))) void*)(ldsw + db + i * 512),
                16, 0, 0);
            __builtin_amdgcn_global_load_lds(
                (const __attribute__((address_space(1))) void*)(sl + i * 512),
                (__attribute__((address_space(3))) void*)(ldsw + db + CHUNK_ELEMS + i * 512),
                16, 0, 0);
        }
    };

// MFMA phase: 16 ds_read_b128 + 48 MFMA into fresh accs P0,P1
#define MFMA_PHASE(BB, MB, P0, P1)                                            \
    {                                                                         \
        P0 = (f32x16){0,0,0,0,0,0,0,0,0,0,0,0,0,0,0,0};                       \
        P1 = (f32x16){0,0,0,0,0,0,0,0,0,0,0,0,0,0,0,0};                       \
        _Pragma("unroll")                                                     \
        for (int ks = 0; ks < 8; ++ks) {                                      \
            const int fo = (BB) + (MB) * 4096 + (ks * 2 + kh) * 256 + ln * 8; \
            s16x8 a_h = *(const s16x8*)&Bs[fo];                               \
            s16x8 a_l = *(const s16x8*)&Bs[CHUNK_ELEMS + fo];                 \
            P0 = __builtin_amdgcn_mfma_f32_32x32x16_bf16(a_h, bh[0][ks], P0, 0, 0, 0); \
            P1 = __builtin_amdgcn_mfma_f32_32x32x16_bf16(a_h, bh[1][ks], P1, 0, 0, 0); \
            P0 = __builtin_amdgcn_mfma_f32_32x32x16_bf16(a_h, bl[0][ks], P0, 0, 0, 0); \
            P1 = __builtin_amdgcn_mfma_f32_32x32x16_bf16(a_h, bl[1][ks], P1, 0, 0, 0); \
            P0 = __builtin_amdgcn_mfma_f32_32x32x16_bf16(a_l, bh[0][ks], P0, 0, 0, 0); \
            P1 = __builtin_amdgcn_mfma_f32_32x32x16_bf16(a_l, bh[1][ks], P1, 0, 0, 0); \
        }                                                                     \
    }

// epilogue for a finished phase: d = acc + cnorm(LDS); per-lane top-2.
// split-local index (sbase applied once at the end).
#define EPI(P0, P1, CB)                                                       \
    {                                                                         \
        _Pragma("unroll")                                                     \
        for (int r = 0; r < 16; ++r) {                                        \
            const int cc = (CB) + ((r & 3) + 8 * (r >> 2));                   \
            const float cn = cns[cc];                                         \
            float d0 = P0[r] + cn;                                            \
            v2[0] = fminf(v2[0], fmaxf(d0, v1[0]));                           \
            if (d0 < v1[0]) j1[0] = cc;                                       \
            v1[0] = fminf(v1[0], d0);                                         \
            float d1 = P1[r] + cn;                                            \
            v2[1] = fminf(v2[1], fmaxf(d1, v1[1]));                           \
            if (d1 < v1[1]) j1[1] = cc;                                       \
            v1[1] = fminf(v1[1], d1);                                         \
        }                                                                     \
    }

    // pipeline state: slot A = mb0 accs, slot B = mb1 accs (one phase behind)
    f32x16 aA0, aA1, aB0, aB1;
    int cbA, cbB;

    // ---- stage chunk 0 into buf 0, peel chunk 0 ----
    stage(0, 0);
    __syncthreads();
    {
        stage(1, 1);
        const int cb = 4 * kh;                 // split-local code base, chunk 0
        MFMA_PHASE(0, 0, aA0, aA1);
        cbA = cb;
        MFMA_PHASE(0, 1, aB0, aB1);
        EPI(aA0, aA1, cbA);                    // epilogue(mb0) under mb1 MFMAs
        cbB = cb + 32;
        __syncthreads();
    }

    for (int c = 1; c < NCHUNK; ++c) {
        const int b = c & 1;
        if (c + 1 < NCHUNK) stage(c + 1, 1 - b);   // async prefetch
        const int bb = b * 2 * CHUNK_ELEMS;
        const int cb = c * 64 + 4 * kh;

        MFMA_PHASE(bb, 0, aA0, aA1);
        EPI(aB0, aB1, cbB);                    // epilogue(prev chunk mb1)
        cbA = cb;
        MFMA_PHASE(bb, 1, aB0, aB1);
        EPI(aA0, aA1, cbA);                    // epilogue(this chunk mb0)
        cbB = cb + 32;
        __syncthreads();                       // buf b reads done; prefetch drained
    }
    EPI(aB0, aB1, cbB);                        // drain last phase

    // merge lane^32 (same sample, other code-subset), emit per-split top-2
#pragma unroll
    for (int g = 0; g < 2; ++g) {
        float ov1 = __shfl_xor(v1[g], 32, 64);
        int   oj1 = __shfl_xor(j1[g], 32, 64);
        float ov2 = __shfl_xor(v2[g], 32, 64);
        float hi = fmaxf(v1[g], ov1);
        v2[g] = fminf(fminf(v2[g], ov2), hi);
        if (ov1 < v1[g] || (ov1 == v1[g] && oj1 < j1[g])) { v1[g] = ov1; j1[g] = oj1; }
        if (kh == 0) {
            int m = m0 + wave * 64 + g * 32 + ln;
            candKey[(size_t)m * NSPLIT + split] =
                ((u64)ordf(v1[g]) << 32) | (unsigned)(sbase + j1[g]);
            cand2[(size_t)m * NSPLIT + split] = ordf(v2[g]);
        }
    }
#undef MFMA_PHASE
#undef EPI
}

// ---- fused finalize + output: merge 8 candidates, flag near-ties, gather, loss ----
// Flagged entries carry an 8-bit mask of "suspicious" splits (v1_s <= v1+TAU)
// -- the only splits that can contain the true argmin. Typically 1 bit set.
__global__ __launch_bounds__(256) void outfin_k(const float* __restrict__ X,
                                                const float* __restrict__ CT,
                                                const u64* __restrict__ candKey,
                                                const unsigned* __restrict__ cand2,
                                                int* __restrict__ idxf,
                                                int* __restrict__ rlist,
                                                int* __restrict__ counter,
                                                float* __restrict__ lossbuf,
                                                float* __restrict__ out) {
    __shared__ float red[4];
    const int t = threadIdx.x;
    const int m = blockIdx.x * 8 + (t >> 5);
    const int l = t & 31;

    int code = 0;
    if (l == 0) {
        u64 best = 0xffffffffffffffffull;
        float v2 = 3.4e38f;
#pragma unroll
        for (int s = 0; s < NSPLIT; ++s) {
            u64 k = candKey[(size_t)m * NSPLIT + s];
            unsigned o2 = cand2[(size_t)m * NSPLIT + s];
            if (k < best) {
                if (best != 0xffffffffffffffffull)
                    v2 = fminf(v2, unordf((unsigned)(best >> 32)));
                best = k;
                v2 = fminf(v2, unordf(o2));
            } else {
                v2 = fminf(v2, unordf((unsigned)(k >> 32)));
            }
        }
        code = (int)(unsigned)(best & 0xffffffffu);
        idxf[m] = code;
        float v1 = unordf((unsigned)(best >> 32));
        if (v2 - v1 <= TAU) {
            const float thr = v1 + TAU;
            int mask = 0;
#pragma unroll
            for (int s = 0; s < NSPLIT; ++s) {
                float v1s = unordf((unsigned)(candKey[(size_t)m * NSPLIT + s] >> 32));
                mask |= (v1s <= thr) ? (1 << s) : 0;
            }
            rlist[atomicAdd(counter, 1)] = m | (mask << 16);
        }
    }
    code = __shfl(code, 0, 32);

    float4 q = *(const float4*)(CT + (size_t)code * EMBED + l * 4);
    float4 x = *(const float4*)(X + (size_t)m * EMBED + l * 4);
    *(float4*)(out + (size_t)m * EMBED + l * 4) = q;
    float dx = q.x - x.x, dy = q.y - x.y, dz = q.z - x.z, dw = q.w - x.w;
    float lsum = dx * dx + dy * dy + dz * dz + dw * dw;
#pragma unroll
    for (int off = 1; off < 64; off <<= 1) lsum += __shfl_xor(lsum, off, 64);
    if ((t & 63) == 0) red[t >> 6] = lsum;
    __syncthreads();
    if (t == 0)
        atomicAdd(&lossbuf[blockIdx.x & 63],
                  (red[0] + red[1] + red[2] + red[3]) * (1.25f / (float)OUT_ELEMS));
}

// ---- rescue2: one block owns one flagged sample end-to-end ----
// Exact fp32 argmin over the suspicious splits (40 iters x 32 rows each),
// then DIRECTLY patches out[m] + loss delta (absorbs old patch_k; no wsBest
// handshake, one less launch+drain). Block 0 also folds lossbuf.
__global__ __launch_bounds__(256) void rescue2(const float* __restrict__ X,
                                               const float* __restrict__ CT,
                                               const float* __restrict__ cnorm,
                                               const int* __restrict__ rlist,
                                               const int* __restrict__ counter,
                                               const int* __restrict__ idxf,
                                               const float* __restrict__ lossbuf,
                                               float* __restrict__ out) {
    __shared__ float xs[EMBED];
    __shared__ u64 wk[4];
    __shared__ int jn_sh;
    const int t = threadIdx.x;
    const int lane = t & 63;
    const int wave = t >> 6;
    const int hw = t & 31;       // lane within half-wave (dims hw*4..hw*4+3)
    const int slot = t >> 5;     // 0..7 row-slot
    if (blockIdx.x == 0 && t == 0) {
        float s = 0.f;
#pragma unroll
        for (int i = 0; i < 64; ++i) s += lossbuf[i];
        atomicAdd(out + OUT_ELEMS, s);
    }
    const int cnt = *counter;

    for (int e = blockIdx.x; e < cnt; e += gridDim.x) {
        const int packed = rlist[e];
        const int m    = packed & 0xffff;
        const int mask = (packed >> 16) & 0xff;
        __syncthreads();   // previous iteration's xs/wk/jn reads complete
        if (t < 32) {
            float4 v = *(const float4*)(X + (size_t)m * EMBED + t * 4);
            xs[t * 4 + 0] = v.x; xs[t * 4 + 1] = v.y;
            xs[t * 4 + 2] = v.z; xs[t * 4 + 3] = v.w;
        }
        __syncthreads();
        const float x0 = xs[hw * 4 + 0], x1 = xs[hw * 4 + 1];
        const float x2 = xs[hw * 4 + 2], x3 = xs[hw * 4 + 3];
        u64 bk = 0xffffffffffffffffull;
        for (int sp = 0; sp < NSPLIT; ++sp) {
            if (!((mask >> sp) & 1)) continue;   // block-uniform
            const int base = sp * SPLIT_CODES;
            for (int it = 0; it < 40; ++it) {    // 40*32 = 1280 codes
                const int r0 = base + it * 32 + slot * 4;
                float4 c0 = *(const float4*)(CT + (size_t)(r0 + 0) * EMBED + hw * 4);
                float4 c1 = *(const float4*)(CT + (size_t)(r0 + 1) * EMBED + hw * 4);
                float4 c2 = *(const float4*)(CT + (size_t)(r0 + 2) * EMBED + hw * 4);
                float4 c3 = *(const float4*)(CT + (size_t)(r0 + 3) * EMBED + hw * 4);
                float p0 = x0 * c0.x, p1 = x0 * c1.x, p2 = x0 * c2.x, p3 = x0 * c3.x;
                p0 = fmaf(x1, c0.y, p0); p1 = fmaf(x1, c1.y, p1);
                p2 = fmaf(x1, c2.y, p2); p3 = fmaf(x1, c3.y, p3);
                p0 = fmaf(x2, c0.z, p0); p1 = fmaf(x2, c1.z, p1);
                p2 = fmaf(x2, c2.z, p2); p3 = fmaf(x2, c3.z, p3);
                p0 = fmaf(x3, c0.w, p0); p1 = fmaf(x3, c1.w, p1);
                p2 = fmaf(x3, c2.w, p2); p3 = fmaf(x3, c3.w, p3);
#pragma unroll
                for (int off = 1; off < 32; off <<= 1) {   // 4 interleaved chains
                    p0 += __shfl_xor(p0, off, 32);
                    p1 += __shfl_xor(p1, off, 32);
                    p2 += __shfl_xor(p2, off, 32);
                    p3 += __shfl_xor(p3, off, 32);
                }
                if (hw == 0) {
                    u64 k;
                    k = ((u64)ordf(fmaf(-2.f, p0, cnorm[r0 + 0])) << 32) | (unsigned)(r0 + 0); if (k < bk) bk = k;
                    k = ((u64)ordf(fmaf(-2.f, p1, cnorm[r0 + 1])) << 32) | (unsigned)(r0 + 1); if (k < bk) bk = k;
                    k = ((u64)ordf(fmaf(-2.f, p2, cnorm[r0 + 2])) << 32) | (unsigned)(r0 + 2); if (k < bk) bk = k;
                    k = ((u64)ordf(fmaf(-2.f, p3, cnorm[r0 + 3])) << 32) | (unsigned)(r0 + 3); if (k < bk) bk = k;
                }
            }
        }
#pragma unroll
        for (int off = 1; off < 64; off <<= 1) {
            u64 o = __shfl_xor(bk, off, 64);
            if (o < bk) bk = o;
        }
        if (lane == 0) wk[wave] = bk;
        __syncthreads();
        if (t == 0) {
            u64 b = wk[0];
            if (wk[1] < b) b = wk[1];
            if (wk[2] < b) b = wk[2];
            if (wk[3] < b) b = wk[3];
            jn_sh = (int)(unsigned)(b & 0xffffffffu);
        }
        __syncthreads();
        const int jn = jn_sh;
        const int jo = idxf[m];
        if (jn != jo && t < 32) {              // apply the flip in-place
            const int l = t;
            float4 qn = *(const float4*)(CT + (size_t)jn * EMBED + l * 4);
            float4 qo = *(const float4*)(CT + (size_t)jo * EMBED + l * 4);
            float4 x  = *(const float4*)(X + (size_t)m * EMBED + l * 4);
            *(float4*)(out + (size_t)m * EMBED + l * 4) = qn;
            float dn = (qn.x - x.x) * (qn.x - x.x) + (qn.y - x.y) * (qn.y - x.y)
                     + (qn.z - x.z) * (qn.z - x.z) + (qn.w - x.w) * (qn.w - x.w);
            float dp = (qo.x - x.x) * (qo.x - x.x) + (qo.y - x.y) * (qo.y - x.y)
                     + (qo.z - x.z) * (qo.z - x.z) + (qo.w - x.w) * (qo.w - x.w);
            float delta = dn - dp;
#pragma unroll
            for (int off = 1; off < 32; off <<= 1) delta += __shfl_xor(delta, off, 32);
            if (l == 0)
                atomicAdd(out + OUT_ELEMS, delta * (1.25f / (float)OUT_ELEMS));
        }
    }
}

extern "C" void kernel_launch(void* const* d_in, const int* in_sizes, int n_in,
                              void* d_out, int out_size, void* d_ws, size_t ws_size,
                              hipStream_t stream) {
    const float* X = (const float*)d_in[0];   // (16384,128) fp32
    const float* C = (const float*)d_in[1];   // (128,10000) fp32
    float* out = (float*)d_out;
    char* ws = (char*)d_ws;

    ushort_t* Ah = (ushort_t*)(ws + OFF_AH);
    ushort_t* Al = (ushort_t*)(ws + OFF_AL);
    float* CT    = (float*)(ws + OFF_CT);
    float* cnorm = (float*)(ws + OFF_CN);
    u64* candKey = (u64*)(ws + OFF_KEY);
    unsigned* cand2 = (unsigned*)(ws + OFF_C2);
    int* idxf    = (int*)(ws + OFF_IDX);
    int* rlist   = (int*)(ws + OFF_RL);
    int* counter = (int*)(ws + OFF_CNT);
    float* lossbuf = (float*)(ws + OFF_LOSS);

    prep_all<<<NCODE_PAD / 16, 256, 0, stream>>>(C, Ah, Al, CT, cnorm, out, counter, lossbuf);
    vq7<<<dim3(NSAMP / 256, NSPLIT), 256, 0, stream>>>(X, Ah, Al, cnorm, candKey, cand2);
    outfin_k<<<NSAMP / 8, 256, 0, stream>>>(X, CT, candKey, cand2, idxf, rlist, counter, lossbuf, out);
    rescue2<<<1024, 256, 0, stream>>>(X, CT, cnorm, rlist, counter, idxf, lossbuf, out);
}

// Round 11
// 218.374 us; speedup vs baseline: 1.2830x; 1.2830x over previous
//
#include <hip/hip_runtime.h>

#define EMBED 128
#define NCODE 10000
#define NSAMP 16384
#define NCODE_PAD 10240
#define NSPLIT 8
#define SPLIT_CODES 1280
#define NCHUNK 20                 // chunks per split, 64 codes each
#define CHUNK_ELEMS 8192          // ushorts per chunk per (h|l): 2mb*8ks*2kh*256
#define OUT_ELEMS (NSAMP * EMBED)
#define TAU 0.002f                // ~28 sigma of full split-bf16 pairwise error

typedef float f32x16 __attribute__((ext_vector_type(16)));
typedef short s16x8 __attribute__((ext_vector_type(8)));
typedef unsigned short ushort_t;
typedef unsigned long long u64;

// ---- ws byte offsets (~12.4 MB) ----
#define OFF_AH  0                 // codes hi bf16, swizzled (2.62 MB)
#define OFF_AL  2621440           // codes lo bf16
#define OFF_CT  5242880           // CT fp32 [n][k] (5.24 MB)
#define OFF_CN  10485760          // cnorm fp32 [10240]
#define OFF_KEY 10526720          // candKey u64 [16384][8]
#define OFF_C2  11575296          // cand2 u32 [16384][8]
#define OFF_IDX 12099584
#define OFF_RL  12165120          // rlist i32 [16384]: m | (splitmask<<16)
#define OFF_CNT 12230656
#define OFF_BEST 12230720         // wsBest u64 [16384]
#define OFF_LOSS 12361792         // lossbuf f32 [64]

__device__ __forceinline__ unsigned short f2bf(float f) {   // RNE fp32->bf16
    unsigned u = __float_as_uint(f);
    return (unsigned short)((u + 0x7fffu + ((u >> 16) & 1u)) >> 16);
}
__device__ __forceinline__ float bf2f(unsigned short h) {
    return __uint_as_float(((unsigned)h) << 16);
}
__device__ __forceinline__ unsigned ordf(float f) {         // order-preserving fp32->u32
    unsigned u = __float_as_uint(f);
    return (u & 0x80000000u) ? ~u : (u | 0x80000000u);
}
__device__ __forceinline__ float unordf(unsigned o) {
    return __uint_as_float((o & 0x80000000u) ? (o ^ 0x80000000u) : ~o);
}

// ---- fused prep: codes -> split-bf16 A-streams + CT fp32 + cnorm ----
// block = 16 codes x 16 dim-groups; cnorm via LDS tree-reduce during the
// conversion pass (no second strided read of C). Also zeroes loss/counter.
__global__ __launch_bounds__(256) void prep_all(const float* __restrict__ C,
                                                ushort_t* __restrict__ Ah,
                                                ushort_t* __restrict__ Al,
                                                float* __restrict__ CT,
                                                float* __restrict__ cnorm,
                                                float* __restrict__ out,
                                                int* __restrict__ counter,
                                                float* __restrict__ lossbuf) {
    __shared__ float red[256];
    const int t  = threadIdx.x;
    const int nl = t & 15;            // code within block
    const int kg = t >> 4;            // 0..15 dim-group
    const int n  = blockIdx.x * 16 + nl;   // 640 blocks
    if (blockIdx.x == 0) {
        if (t == 0) { out[OUT_ELEMS] = 0.f; *counter = 0; }
        if (t < 64) lossbuf[t] = 0.f;
    }

    const int split = n / SPLIT_CODES;
    const int rem   = n % SPLIT_CODES;
    const int chunk = rem >> 6;
    const int mb    = (rem >> 5) & 1;
    const int row   = rem & 31;
    const int ks = kg >> 1, kh = kg & 1;
    const size_t eoff = (size_t)(split * NCHUNK + chunk) * CHUNK_ELEMS
                      + (size_t)(mb * 4096 + (ks * 2 + kh) * 256 + row * 8);
    const int k0 = kg * 8;
    float f[8];
    float s = 0.f;
#pragma unroll
    for (int j = 0; j < 8; ++j) {
        f[j] = (n < NCODE) ? C[(size_t)(k0 + j) * NCODE + n] : 0.f;
        s = fmaf(f[j], f[j], s);
    }
    *(float4*)(CT + (size_t)n * EMBED + k0)     = make_float4(f[0], f[1], f[2], f[3]);
    *(float4*)(CT + (size_t)n * EMBED + k0 + 4) = make_float4(f[4], f[5], f[6], f[7]);
    s16x8 vh, vl;
#pragma unroll
    for (int j = 0; j < 8; ++j) {
        unsigned short h = f2bf(f[j]);
        vh[j] = (short)h;
        vl[j] = (short)f2bf(f[j] - bf2f(h));
    }
    *(s16x8*)(Ah + eoff) = vh;
    *(s16x8*)(Al + eoff) = vl;

    // cnorm: reduce s over the 16 dim-groups of each code
    red[t] = s;
    __syncthreads();
    if (t < 128) red[t] += red[t + 128];
    __syncthreads();
    if (t < 64) red[t] += red[t + 64];
    __syncthreads();
    if (t < 32) red[t] += red[t + 32];
    __syncthreads();
    if (t < 16) {
        const int nn = blockIdx.x * 16 + t;
        cnorm[nn] = (nn < NCODE) ? (red[t] + red[t + 16]) : 3.0e38f;
    }
}

// ---- main: persistent-X (B, -2x split h+l), codes (A, split h+l) LDS dbuf ----
// dist = cnorm (exact, epilogue) + [AhBh + AhBl + AlBh]. Argmin per-lane.
// Shell frozen at R18 (measured: 120.5-124 us, MfmaUtil 48-50, no spill).
__global__ __launch_bounds__(256, 2) void vq7(const float* __restrict__ X,
                                              const ushort_t* __restrict__ Ah,
                                              const ushort_t* __restrict__ Al,
                                              const float* __restrict__ cnorm,
                                              u64* __restrict__ candKey,
                                              unsigned* __restrict__ cand2) {
    __shared__ ushort_t Bs[2 * 2 * CHUNK_ELEMS];   // 64 KB: buf{0,1} x {h,l}
    __shared__ float cns[SPLIT_CODES];             // 5 KB cnorm slice
    const int t    = threadIdx.x;
    const int lane = t & 63;
    const int wave = t >> 6;
    const int ln   = lane & 31;
    const int kh   = lane >> 5;
    const int split = blockIdx.y;
    const int m0    = blockIdx.x * 256;
    const int sbase = split * SPLIT_CODES;

    // ---- persistent B frags: (-2x) RNE-split hi+lo (128 VGPR) ----
    s16x8 bh[2][8], bl[2][8];
#pragma unroll
    for (int g = 0; g < 2; ++g) {
        int m = m0 + wave * 64 + g * 32 + ln;
#pragma unroll
        for (int ks = 0; ks < 8; ++ks) {
            const float* src = X + (size_t)m * EMBED + ks * 16 + kh * 8;
            float4 f0 = *(const float4*)src;
            float4 f1 = *(const float4*)(src + 4);
            float f[8] = {f0.x, f0.y, f0.z, f0.w, f1.x, f1.y, f1.z, f1.w};
            s16x8 vh, vl;
#pragma unroll
            for (int j = 0; j < 8; ++j) {
                float v = -2.f * f[j];
                unsigned short h = f2bf(v);
                vh[j] = (short)h;
                vl[j] = (short)f2bf(v - bf2f(h));
            }
            bh[g][ks] = vh;
            bl[g][ks] = vl;
        }
    }

    // cnorm slice -> LDS (visible after the prologue __syncthreads)
    for (int i = t; i < SPLIT_CODES; i += 256) cns[i] = cnorm[sbase + i];

    float v1[2] = {3.4e38f, 3.4e38f}, v2[2] = {3.4e38f, 3.4e38f};
    int   j1[2] = {0, 0};

    auto ldsw = (__attribute__((address_space(3))) ushort_t*)Bs;
    const int woff = wave * 2048;              // 4 KB slice per wave per {h,l}
    const size_t chbase = (size_t)(split * NCHUNK) * CHUNK_ELEMS;

    auto stage = [&](int cc, int buf) {
        const size_t sb = chbase + (size_t)cc * CHUNK_ELEMS;
        const ushort_t* sh = Ah + sb + woff + lane * 8;
        const ushort_t* sl = Al + sb + woff + lane * 8;
        const int db = buf * 2 * CHUNK_ELEMS + woff;
#pragma unroll
        for (int i = 0; i < 4; ++i) {
            __builtin_amdgcn_global_load_lds(
                (const __attribute__((address_space(1))) void*)(sh + i * 512),
                (__attribute__((address_space(3))) void*)(ldsw + db + i * 512),
                16, 0, 0);
            __builtin_amdgcn_global_load_lds(
                (const __attribute__((address_space(1))) void*)(sl + i * 512),
                (__attribute__((address_space(3))) void*)(ldsw + db + CHUNK_ELEMS + i * 512),
                16, 0, 0);
        }
    };

// MFMA phase: 16 ds_read_b128 + 48 MFMA into fresh accs P0,P1
#define MFMA_PHASE(BB, MB, P0, P1)                                            \
    {                                                                         \
        P0 = (f32x16){0,0,0,0,0,0,0,0,0,0,0,0,0,0,0,0};                       \
        P1 = (f32x16){0,0,0,0,0,0,0,0,0,0,0,0,0,0,0,0};                       \
        _Pragma("unroll")                                                     \
        for (int ks = 0; ks < 8; ++ks) {                                      \
            const int fo = (BB) + (MB) * 4096 + (ks * 2 + kh) * 256 + ln * 8; \
            s16x8 a_h = *(const s16x8*)&Bs[fo];                               \
            s16x8 a_l = *(const s16x8*)&Bs[CHUNK_ELEMS + fo];                 \
            P0 = __builtin_amdgcn_mfma_f32_32x32x16_bf16(a_h, bh[0][ks], P0, 0, 0, 0); \
            P1 = __builtin_amdgcn_mfma_f32_32x32x16_bf16(a_h, bh[1][ks], P1, 0, 0, 0); \
            P0 = __builtin_amdgcn_mfma_f32_32x32x16_bf16(a_h, bl[0][ks], P0, 0, 0, 0); \
            P1 = __builtin_amdgcn_mfma_f32_32x32x16_bf16(a_h, bl[1][ks], P1, 0, 0, 0); \
            P0 = __builtin_amdgcn_mfma_f32_32x32x16_bf16(a_l, bh[0][ks], P0, 0, 0, 0); \
            P1 = __builtin_amdgcn_mfma_f32_32x32x16_bf16(a_l, bh[1][ks], P1, 0, 0, 0); \
        }                                                                     \
    }

// epilogue for a finished phase: d = acc + cnorm(LDS); per-lane top-2.
// split-local index (sbase applied once at the end).
#define EPI(P0, P1, CB)                                                       \
    {                                                                         \
        _Pragma("unroll")                                                     \
        for (int r = 0; r < 16; ++r) {                                        \
            const int cc = (CB) + ((r & 3) + 8 * (r >> 2));                   \
            const float cn = cns[cc];                                         \
            float d0 = P0[r] + cn;                                            \
            v2[0] = fminf(v2[0], fmaxf(d0, v1[0]));                           \
            if (d0 < v1[0]) j1[0] = cc;                                       \
            v1[0] = fminf(v1[0], d0);                                         \
            float d1 = P1[r] + cn;                                            \
            v2[1] = fminf(v2[1], fmaxf(d1, v1[1]));                           \
            if (d1 < v1[1]) j1[1] = cc;                                       \
            v1[1] = fminf(v1[1], d1);                                         \
        }                                                                     \
    }

    // pipeline state: slot A = mb0 accs, slot B = mb1 accs (one phase behind)
    f32x16 aA0, aA1, aB0, aB1;
    int cbA, cbB;

    // ---- stage chunk 0 into buf 0, peel chunk 0 ----
    stage(0, 0);
    __syncthreads();
    {
        stage(1, 1);
        const int cb = 4 * kh;                 // split-local code base, chunk 0
        MFMA_PHASE(0, 0, aA0, aA1);
        cbA = cb;
        MFMA_PHASE(0, 1, aB0, aB1);
        EPI(aA0, aA1, cbA);                    // epilogue(mb0) under mb1 MFMAs
        cbB = cb + 32;
        __syncthreads();
    }

    for (int c = 1; c < NCHUNK; ++c) {
        const int b = c & 1;
        if (c + 1 < NCHUNK) stage(c + 1, 1 - b);   // async prefetch
        const int bb = b * 2 * CHUNK_ELEMS;
        const int cb = c * 64 + 4 * kh;

        MFMA_PHASE(bb, 0, aA0, aA1);
        EPI(aB0, aB1, cbB);                    // epilogue(prev chunk mb1)
        cbA = cb;
        MFMA_PHASE(bb, 1, aB0, aB1);
        EPI(aA0, aA1, cbA);                    // epilogue(this chunk mb0)
        cbB = cb + 32;
        __syncthreads();                       // buf b reads done; prefetch drained
    }
    EPI(aB0, aB1, cbB);                        // drain last phase

    // merge lane^32 (same sample, other code-subset), emit per-split top-2
#pragma unroll
    for (int g = 0; g < 2; ++g) {
        float ov1 = __shfl_xor(v1[g], 32, 64);
        int   oj1 = __shfl_xor(j1[g], 32, 64);
        float ov2 = __shfl_xor(v2[g], 32, 64);
        float hi = fmaxf(v1[g], ov1);
        v2[g] = fminf(fminf(v2[g], ov2), hi);
        if (ov1 < v1[g] || (ov1 == v1[g] && oj1 < j1[g])) { v1[g] = ov1; j1[g] = oj1; }
        if (kh == 0) {
            int m = m0 + wave * 64 + g * 32 + ln;
            candKey[(size_t)m * NSPLIT + split] =
                ((u64)ordf(v1[g]) << 32) | (unsigned)(sbase + j1[g]);
            cand2[(size_t)m * NSPLIT + split] = ordf(v2[g]);
        }
    }
#undef MFMA_PHASE
#undef EPI
}

// ---- fused finalize + output: merge 8 candidates, flag near-ties, gather, loss ----
// Flagged entries carry an 8-bit mask of "suspicious" splits (v1_s <= v1+TAU)
// -- the only splits that can contain the true argmin. Typically 1 bit set.
__global__ __launch_bounds__(256) void outfin_k(const float* __restrict__ X,
                                                const float* __restrict__ CT,
                                                const u64* __restrict__ candKey,
                                                const unsigned* __restrict__ cand2,
                                                int* __restrict__ idxf,
                                                int* __restrict__ rlist,
                                                int* __restrict__ counter,
                                                u64* __restrict__ wsBest,
                                                float* __restrict__ lossbuf,
                                                float* __restrict__ out) {
    __shared__ float red[4];
    const int t = threadIdx.x;
    const int m = blockIdx.x * 8 + (t >> 5);
    const int l = t & 31;

    int code = 0;
    if (l == 0) {
        u64 best = 0xffffffffffffffffull;
        float v2 = 3.4e38f;
#pragma unroll
        for (int s = 0; s < NSPLIT; ++s) {
            u64 k = candKey[(size_t)m * NSPLIT + s];
            unsigned o2 = cand2[(size_t)m * NSPLIT + s];
            if (k < best) {
                if (best != 0xffffffffffffffffull)
                    v2 = fminf(v2, unordf((unsigned)(best >> 32)));
                best = k;
                v2 = fminf(v2, unordf(o2));
            } else {
                v2 = fminf(v2, unordf((unsigned)(k >> 32)));
            }
        }
        code = (int)(unsigned)(best & 0xffffffffu);
        idxf[m] = code;
        float v1 = unordf((unsigned)(best >> 32));
        if (v2 - v1 <= TAU) {
            const float thr = v1 + TAU;
            int mask = 0;
#pragma unroll
            for (int s = 0; s < NSPLIT; ++s) {
                float v1s = unordf((unsigned)(candKey[(size_t)m * NSPLIT + s] >> 32));
                mask |= (v1s <= thr) ? (1 << s) : 0;
            }
            rlist[atomicAdd(counter, 1)] = m | (mask << 16);
            wsBest[m] = 0xffffffffffffffffull;   // init for rescue atomicMin
        }
    }
    code = __shfl(code, 0, 32);

    float4 q = *(const float4*)(CT + (size_t)code * EMBED + l * 4);
    float4 x = *(const float4*)(X + (size_t)m * EMBED + l * 4);
    *(float4*)(out + (size_t)m * EMBED + l * 4) = q;
    float dx = q.x - x.x, dy = q.y - x.y, dz = q.z - x.z, dw = q.w - x.w;
    float lsum = dx * dx + dy * dy + dz * dz + dw * dw;
#pragma unroll
    for (int off = 1; off < 64; off <<= 1) lsum += __shfl_xor(lsum, off, 64);
    if ((t & 63) == 0) red[t >> 6] = lsum;
    __syncthreads();
    if (t == 0)
        atomicAdd(&lossbuf[blockIdx.x & 63],
                  (red[0] + red[1] + red[2] + red[3]) * (1.25f / (float)OUT_ELEMS));
}

// ---- rescue: exact fp32 argmin over suspicious splits only ----
// work unit = (entry, split, half): 640 codes, 20 iters x 32 rows in flight.
// Pad codes (>= NCODE) are guarded by cnorm = 3e38 -- no bounds checks.
__global__ __launch_bounds__(256) void rescue_seg(const float* __restrict__ X,
                                                  const float* __restrict__ CT,
                                                  const float* __restrict__ cnorm,
                                                  const int* __restrict__ rlist,
                                                  const int* __restrict__ counter,
                                                  u64* __restrict__ wsBest) {
    __shared__ float xs[EMBED];
    __shared__ u64 wk[4];
    const int t = threadIdx.x;
    const int lane = t & 63;
    const int wave = t >> 6;
    const int hw = t & 31;       // lane within half-wave (dims hw*4..hw*4+3)
    const int slot = t >> 5;     // 0..7 row-slot
    const int cnt = *counter;
    const int nw = cnt * 16;     // entry x split(8) x half(2)

    for (int w = blockIdx.x; w < nw; w += gridDim.x) {
        const int e  = w >> 4;
        const int sp = (w >> 1) & 7;
        const int hf = w & 1;
        const int packed = rlist[e];
        if (!((packed >> (16 + sp)) & 1)) continue;   // block-uniform skip
        const int m = packed & 0xffff;
        __syncthreads();   // previous iteration's xs/wk reads complete
        if (t < 32) {
            float4 v = *(const float4*)(X + (size_t)m * EMBED + t * 4);
            xs[t * 4 + 0] = v.x; xs[t * 4 + 1] = v.y;
            xs[t * 4 + 2] = v.z; xs[t * 4 + 3] = v.w;
        }
        __syncthreads();
        const float x0 = xs[hw * 4 + 0], x1 = xs[hw * 4 + 1];
        const float x2 = xs[hw * 4 + 2], x3 = xs[hw * 4 + 3];
        const int base = sp * SPLIT_CODES + hf * 640;
        u64 bk = 0xffffffffffffffffull;
        for (int it = 0; it < 20; ++it) {
            const int r0 = base + it * 32 + slot * 4;
            float4 c0 = *(const float4*)(CT + (size_t)(r0 + 0) * EMBED + hw * 4);
            float4 c1 = *(const float4*)(CT + (size_t)(r0 + 1) * EMBED + hw * 4);
            float4 c2 = *(const float4*)(CT + (size_t)(r0 + 2) * EMBED + hw * 4);
            float4 c3 = *(const float4*)(CT + (size_t)(r0 + 3) * EMBED + hw * 4);
            float p0 = x0 * c0.x, p1 = x0 * c1.x, p2 = x0 * c2.x, p3 = x0 * c3.x;
            p0 = fmaf(x1, c0.y, p0); p1 = fmaf(x1, c1.y, p1);
            p2 = fmaf(x1, c2.y, p2); p3 = fmaf(x1, c3.y, p3);
            p0 = fmaf(x2, c0.z, p0); p1 = fmaf(x2, c1.z, p1);
            p2 = fmaf(x2, c2.z, p2); p3 = fmaf(x2, c3.z, p3);
            p0 = fmaf(x3, c0.w, p0); p1 = fmaf(x3, c1.w, p1);
            p2 = fmaf(x3, c2.w, p2); p3 = fmaf(x3, c3.w, p3);
#pragma unroll
            for (int off = 1; off < 32; off <<= 1) {   // 4 interleaved chains
                p0 += __shfl_xor(p0, off, 32);
                p1 += __shfl_xor(p1, off, 32);
                p2 += __shfl_xor(p2, off, 32);
                p3 += __shfl_xor(p3, off, 32);
            }
            if (hw == 0) {
                u64 k;
                k = ((u64)ordf(fmaf(-2.f, p0, cnorm[r0 + 0])) << 32) | (unsigned)(r0 + 0); if (k < bk) bk = k;
                k = ((u64)ordf(fmaf(-2.f, p1, cnorm[r0 + 1])) << 32) | (unsigned)(r0 + 1); if (k < bk) bk = k;
                k = ((u64)ordf(fmaf(-2.f, p2, cnorm[r0 + 2])) << 32) | (unsigned)(r0 + 2); if (k < bk) bk = k;
                k = ((u64)ordf(fmaf(-2.f, p3, cnorm[r0 + 3])) << 32) | (unsigned)(r0 + 3); if (k < bk) bk = k;
            }
        }
#pragma unroll
        for (int off = 1; off < 64; off <<= 1) {
            u64 o = __shfl_xor(bk, off, 64);
            if (o < bk) bk = o;
        }
        if (lane == 0) wk[wave] = bk;
        __syncthreads();
        if (t == 0) {
            u64 b = wk[0];
            if (wk[1] < b) b = wk[1];
            if (wk[2] < b) b = wk[2];
            if (wk[3] < b) b = wk[3];
            atomicMin(&wsBest[m], b);
        }
    }
}

// ---- patch: fold lossbuf, then apply argmin flips found by rescue ----
__global__ __launch_bounds__(256) void patch_k(const float* __restrict__ X,
                                               const float* __restrict__ CT,
                                               const int* __restrict__ rlist,
                                               const int* __restrict__ counter,
                                               const u64* __restrict__ wsBest,
                                               const int* __restrict__ idxf,
                                               const float* __restrict__ lossbuf,
                                               float* __restrict__ out) {
    const int t = threadIdx.x;
    const int l = t & 31, sl = t >> 5;
    if (blockIdx.x == 0 && t == 0) {
        float s = 0.f;
#pragma unroll
        for (int i = 0; i < 64; ++i) s += lossbuf[i];
        atomicAdd(out + OUT_ELEMS, s);
    }
    const int cnt = *counter;
    for (int s = blockIdx.x * 8 + sl; s < cnt; s += gridDim.x * 8) {
        int m = rlist[s] & 0xffff;
        u64 key = wsBest[m];
        int jn = (int)(unsigned)(key & 0xffffffffu);
        int jo = idxf[m];
        if (jn == jo) continue;   // uniform within 32-lane group
        float4 qn = *(const float4*)(CT + (size_t)jn * EMBED + l * 4);
        float4 qo = *(const float4*)(CT + (size_t)jo * EMBED + l * 4);
        float4 x  = *(const float4*)(X + (size_t)m * EMBED + l * 4);
        *(float4*)(out + (size_t)m * EMBED + l * 4) = qn;
        float dn = (qn.x - x.x) * (qn.x - x.x) + (qn.y - x.y) * (qn.y - x.y)
                 + (qn.z - x.z) * (qn.z - x.z) + (qn.w - x.w) * (qn.w - x.w);
        float dp = (qo.x - x.x) * (qo.x - x.x) + (qo.y - x.y) * (qo.y - x.y)
                 + (qo.z - x.z) * (qo.z - x.z) + (qo.w - x.w) * (qo.w - x.w);
        float delta = dn - dp;
#pragma unroll
        for (int off = 1; off < 32; off <<= 1) delta += __shfl_xor(delta, off, 32);
        if (l == 0)
            atomicAdd(out + OUT_ELEMS, delta * (1.25f / (float)OUT_ELEMS));
    }
}

extern "C" void kernel_launch(void* const* d_in, const int* in_sizes, int n_in,
                              void* d_out, int out_size, void* d_ws, size_t ws_size,
                              hipStream_t stream) {
    const float* X = (const float*)d_in[0];   // (16384,128) fp32
    const float* C = (const float*)d_in[1];   // (128,10000) fp32
    float* out = (float*)d_out;
    char* ws = (char*)d_ws;

    ushort_t* Ah = (ushort_t*)(ws + OFF_AH);
    ushort_t* Al = (ushort_t*)(ws + OFF_AL);
    float* CT    = (float*)(ws + OFF_CT);
    float* cnorm = (float*)(ws + OFF_CN);
    u64* candKey = (u64*)(ws + OFF_KEY);
    unsigned* cand2 = (unsigned*)(ws + OFF_C2);
    int* idxf    = (int*)(ws + OFF_IDX);
    int* rlist   = (int*)(ws + OFF_RL);
    int* counter = (int*)(ws + OFF_CNT);
    u64* wsBest  = (u64*)(ws + OFF_BEST);
    float* lossbuf = (float*)(ws + OFF_LOSS);

    prep_all<<<NCODE_PAD / 16, 256, 0, stream>>>(C, Ah, Al, CT, cnorm, out, counter, lossbuf);
    vq7<<<dim3(NSAMP / 256, NSPLIT), 256, 0, stream>>>(X, Ah, Al, cnorm, candKey, cand2);
    outfin_k<<<NSAMP / 8, 256, 0, stream>>>(X, CT, candKey, cand2, idxf, rlist, counter, wsBest, lossbuf, out);
    rescue_seg<<<1024, 256, 0, stream>>>(X, CT, cnorm, rlist, counter, wsBest);
    patch_k<<<64, 256, 0, stream>>>(X, CT, rlist, counter, wsBest, idxf, lossbuf, out);
}